// Round 1
// baseline (2376.070 us; speedup 1.0000x reference)
//
#include <hip/hip_runtime.h>
#include <math.h>

#define EMBED 1024
#define HEADS 16
#define HDIM  64
#define BATCH 4
#define SEQL  2048
#define MROWS (BATCH*SEQL)   // 8192

// ---------------------------------------------------------------------------
// GEMM: C[m][n] = sum_k X[m][k] * W[n][k] + bias[n]   (i.e. X @ W^T + b)
// Both X and W are row-major with K contiguous (torch Linear weight layout).
// MODE 0: out[m*EMBED + n]                          (plain row-major)
// MODE 1: out[((b*HEADS+h)*SEQL + t)*HDIM + d]      (B,H,T,D remap for attn)
// Tile: BM=BN=128, BK=32; 256 threads; 8x8 frag (2x2 blocks of 4x4).
// LDS pad 33: a-reads 16-lane broadcast, b-reads 2-way (free).
// ---------------------------------------------------------------------------
template<int MODE>
__global__ __launch_bounds__(256, 3)
void gemm_xwt(const float* __restrict__ X, const float* __restrict__ W,
              const float* __restrict__ bias, float* __restrict__ out)
{
  __shared__ float As[128][33];
  __shared__ float Bs[128][33];
  const int tid = threadIdx.x;
  const int tx = tid & 15, ty = tid >> 4;
  const int bm = blockIdx.x * 128;
  const int bn = blockIdx.y * 128;
  const int lrow = tid >> 3;        // 0..31
  const int lc   = (tid & 7) << 2;  // 0,4,...,28

  float acc[8][8];
#pragma unroll
  for (int i = 0; i < 8; ++i)
#pragma unroll
    for (int j = 0; j < 8; ++j) acc[i][j] = 0.f;

  for (int k0 = 0; k0 < EMBED; k0 += 32) {
    __syncthreads();
#pragma unroll
    for (int p = 0; p < 4; ++p) {
      const int row = lrow + p * 32;
      const float4 va = *reinterpret_cast<const float4*>(
          &X[(size_t)(bm + row) * EMBED + k0 + lc]);
      As[row][lc] = va.x; As[row][lc+1] = va.y; As[row][lc+2] = va.z; As[row][lc+3] = va.w;
      const float4 vb = *reinterpret_cast<const float4*>(
          &W[(size_t)(bn + row) * EMBED + k0 + lc]);
      Bs[row][lc] = vb.x; Bs[row][lc+1] = vb.y; Bs[row][lc+2] = vb.z; Bs[row][lc+3] = vb.w;
    }
    __syncthreads();
#pragma unroll 2
    for (int kk = 0; kk < 32; ++kk) {
      float a[8], b[8];
#pragma unroll
      for (int i = 0; i < 4; ++i) { a[i] = As[ty*4 + i][kk]; a[4+i] = As[64 + ty*4 + i][kk]; }
#pragma unroll
      for (int j = 0; j < 4; ++j) { b[j] = Bs[tx*4 + j][kk]; b[4+j] = Bs[64 + tx*4 + j][kk]; }
#pragma unroll
      for (int i = 0; i < 8; ++i)
#pragma unroll
        for (int j = 0; j < 8; ++j) acc[i][j] = fmaf(a[i], b[j], acc[i][j]);
    }
  }

#pragma unroll
  for (int ib = 0; ib < 2; ++ib)
#pragma unroll
    for (int i = 0; i < 4; ++i) {
      const int m = bm + ib*64 + ty*4 + i;
#pragma unroll
      for (int jb = 0; jb < 2; ++jb) {
        const int n0 = bn + jb*64 + tx*4;
        const float4 bv = *reinterpret_cast<const float4*>(&bias[n0]);
        float4 v;
        v.x = acc[ib*4+i][jb*4+0] + bv.x;
        v.y = acc[ib*4+i][jb*4+1] + bv.y;
        v.z = acc[ib*4+i][jb*4+2] + bv.z;
        v.w = acc[ib*4+i][jb*4+3] + bv.w;
        if (MODE == 0) {
          *reinterpret_cast<float4*>(&out[(size_t)m * EMBED + n0]) = v;
        } else {
          const int b = m >> 11;             // m / SEQL
          const int t = m & (SEQL - 1);
          const int h = n0 >> 6;             // n0 / HDIM
          const int d = n0 & (HDIM - 1);
          *reinterpret_cast<float4*>(
              &out[(((size_t)(b * HEADS + h)) * SEQL + t) * HDIM + d]) = v;
        }
      }
    }
}

// ---------------------------------------------------------------------------
// Flash attention, fp32. Q/K/V in (B,H,T,D) from projections; O in (B,T,E).
// Block: 256 threads; Q tile = 64 rows; KV tile = 64; online softmax.
// LDS: Qs[64][65] + Ks[64][65] (reused for P after S-phase) + Vs[64][64]
//      = 49.7 KB -> 3 blocks/CU.
// Row reductions via __shfl_xor width 16 (row group = 16 consecutive lanes).
// Scale 1/sqrt(64)=0.125 folded into Q at load.
// ---------------------------------------------------------------------------
__global__ __launch_bounds__(256, 3)
void flash_attn(const float* __restrict__ Q, const float* __restrict__ K,
                const float* __restrict__ V, float* __restrict__ O)
{
  __shared__ float Qs[64][65];
  __shared__ float Ks[64][65];   // holds K tile, then P tile
  __shared__ float Vs[64][64];

  const int tid = threadIdx.x;
  const int tx = tid & 15, ty = tid >> 4;
  const int bh = blockIdx.y;            // b*HEADS + h
  const int q0 = blockIdx.x * 64;
  const size_t base = (size_t)bh * SEQL * HDIM;

  const int lr = tid >> 4;              // 0..15
  const int lc = (tid & 15) << 2;       // 0..60

#pragma unroll
  for (int p = 0; p < 4; ++p) {
    const int row = lr + p * 16;
    const float4 v = *reinterpret_cast<const float4*>(
        &Q[base + (size_t)(q0 + row) * HDIM + lc]);
    Qs[row][lc]   = v.x * 0.125f; Qs[row][lc+1] = v.y * 0.125f;
    Qs[row][lc+2] = v.z * 0.125f; Qs[row][lc+3] = v.w * 0.125f;
  }

  float m[4], l[4], o[4][4];
#pragma unroll
  for (int i = 0; i < 4; ++i) {
    m[i] = -INFINITY; l[i] = 0.f;
#pragma unroll
    for (int j = 0; j < 4; ++j) o[i][j] = 0.f;
  }

  for (int s0 = 0; s0 < SEQL; s0 += 64) {
    __syncthreads();   // previous iteration fully done with Ks/Vs
#pragma unroll
    for (int p = 0; p < 4; ++p) {
      const int row = lr + p * 16;
      const float4 kv = *reinterpret_cast<const float4*>(
          &K[base + (size_t)(s0 + row) * HDIM + lc]);
      Ks[row][lc] = kv.x; Ks[row][lc+1] = kv.y; Ks[row][lc+2] = kv.z; Ks[row][lc+3] = kv.w;
      const float4 vv = *reinterpret_cast<const float4*>(
          &V[base + (size_t)(s0 + row) * HDIM + lc]);
      *reinterpret_cast<float4*>(&Vs[row][lc]) = vv;
    }
    __syncthreads();

    // S = (Q*scale) . K^T   -- 4x4 frag per thread
    float s[4][4];
#pragma unroll
    for (int i = 0; i < 4; ++i)
#pragma unroll
      for (int j = 0; j < 4; ++j) s[i][j] = 0.f;

#pragma unroll 2
    for (int d = 0; d < HDIM; ++d) {
      float a[4], b[4];
#pragma unroll
      for (int i = 0; i < 4; ++i) a[i] = Qs[ty*4 + i][d];
#pragma unroll
      for (int j = 0; j < 4; ++j) b[j] = Ks[tx*4 + j][d];
#pragma unroll
      for (int i = 0; i < 4; ++i)
#pragma unroll
        for (int j = 0; j < 4; ++j) s[i][j] = fmaf(a[i], b[j], s[i][j]);
    }

    // online softmax update (per row; rows replicated across the 16 tx lanes)
#pragma unroll
    for (int i = 0; i < 4; ++i) {
      float rm = fmaxf(fmaxf(s[i][0], s[i][1]), fmaxf(s[i][2], s[i][3]));
#pragma unroll
      for (int msk = 1; msk < 16; msk <<= 1) rm = fmaxf(rm, __shfl_xor(rm, msk, 16));
      const float mn = fmaxf(m[i], rm);
      const float alpha = __expf(m[i] - mn);
      float sum = 0.f;
#pragma unroll
      for (int j = 0; j < 4; ++j) { s[i][j] = __expf(s[i][j] - mn); sum += s[i][j]; }
#pragma unroll
      for (int msk = 1; msk < 16; msk <<= 1) sum += __shfl_xor(sum, msk, 16);
      l[i] = l[i] * alpha + sum;
      m[i] = mn;
#pragma unroll
      for (int j = 0; j < 4; ++j) o[i][j] *= alpha;
    }

    __syncthreads();   // all threads done reading Ks as K
#pragma unroll
    for (int i = 0; i < 4; ++i)
#pragma unroll
      for (int j = 0; j < 4; ++j) Ks[ty*4 + i][tx*4 + j] = s[i][j];
    __syncthreads();   // P visible to all

    // O += P . V
#pragma unroll 2
    for (int kk = 0; kk < 64; ++kk) {
      float pp[4];
#pragma unroll
      for (int i = 0; i < 4; ++i) pp[i] = Ks[ty*4 + i][kk];
      const float4 vv = *reinterpret_cast<const float4*>(&Vs[kk][tx*4]);
#pragma unroll
      for (int i = 0; i < 4; ++i) {
        o[i][0] = fmaf(pp[i], vv.x, o[i][0]);
        o[i][1] = fmaf(pp[i], vv.y, o[i][1]);
        o[i][2] = fmaf(pp[i], vv.z, o[i][2]);
        o[i][3] = fmaf(pp[i], vv.w, o[i][3]);
      }
    }
  }

  const int b = bh >> 4, h = bh & 15;
#pragma unroll
  for (int i = 0; i < 4; ++i) {
    const float inv = 1.f / l[i];
    const int t = q0 + ty*4 + i;
    float4 v;
    v.x = o[i][0]*inv; v.y = o[i][1]*inv; v.z = o[i][2]*inv; v.w = o[i][3]*inv;
    *reinterpret_cast<float4*>(
        &O[((size_t)b * SEQL + t) * EMBED + h * HDIM + tx*4]) = v;
  }
}

// ---------------------------------------------------------------------------
extern "C" void kernel_launch(void* const* d_in, const int* in_sizes, int n_in,
                              void* d_out, int out_size, void* d_ws, size_t ws_size,
                              hipStream_t stream)
{
  const float* query = (const float*)d_in[0];
  const float* key   = (const float*)d_in[1];
  const float* value = (const float*)d_in[2];
  const float* Wq    = (const float*)d_in[3];
  const float* bq    = (const float*)d_in[4];
  const float* Wk    = (const float*)d_in[5];
  const float* bk    = (const float*)d_in[6];
  const float* Wv    = (const float*)d_in[7];
  const float* bv    = (const float*)d_in[8];
  const float* Wo    = (const float*)d_in[9];
  const float* bo    = (const float*)d_in[10];
  float* out = (float*)d_out;

  // workspace: Q,K,V in (B,H,T,D), attn-out in (B,T,E) -> 4 * 32 MiB = 128 MiB
  const size_t elems = (size_t)MROWS * EMBED;
  float* Qp = (float*)d_ws;
  float* Kp = Qp + elems;
  float* Vp = Kp + elems;
  float* Op = Vp + elems;

  const dim3 gg(MROWS / 128, EMBED / 128);   // (64, 8)
  const dim3 gb(256);

  gemm_xwt<1><<<gg, gb, 0, stream>>>(query, Wq, bq, Qp);
  gemm_xwt<1><<<gg, gb, 0, stream>>>(key,   Wk, bk, Kp);
  gemm_xwt<1><<<gg, gb, 0, stream>>>(value, Wv, bv, Vp);

  flash_attn<<<dim3(SEQL / 64, BATCH * HEADS), gb, 0, stream>>>(Qp, Kp, Vp, Op);

  gemm_xwt<0><<<gg, gb, 0, stream>>>(Op, Wo, bo, out);
}

// Round 3
// 460.973 us; speedup vs baseline: 5.1545x; 5.1545x over previous
//
#include <hip/hip_runtime.h>
#include <math.h>
#include <stdint.h>

#define EMBED 1024
#define HEADS 16
#define HDIM  64
#define BATCH 4
#define SEQL  2048
#define MROWS (BATCH*SEQL)   // 8192

typedef unsigned short u16;
typedef __bf16 bf16x8 __attribute__((ext_vector_type(8)));   // 4 VGPR MFMA operand
typedef float  f32x16 __attribute__((ext_vector_type(16)));  // 32x32 accumulator
typedef u16    u16x8  __attribute__((ext_vector_type(8)));

using gu32 = const __attribute__((address_space(1))) uint32_t;
using lu32 = __attribute__((address_space(3))) uint32_t;

// fp32 -> bf16 round-to-nearest-even
__device__ __forceinline__ u16 f2b(float f) {
  union { float f; uint32_t u; } c; c.f = f;
  return (u16)((c.u + 0x7fffu + ((c.u >> 16) & 1u)) >> 16);
}
__device__ __forceinline__ uint32_t pk2(float lo, float hi) {
  return (uint32_t)f2b(lo) | ((uint32_t)f2b(hi) << 16);
}

// ---------------------------------------------------------------------------
// fp32 -> bf16 conversion (vectorized, grid-stride)
// ---------------------------------------------------------------------------
__global__ void cvt_bf16(const float* __restrict__ in, u16* __restrict__ out, int n4) {
  int i = blockIdx.x * blockDim.x + threadIdx.x;
  const int stride = gridDim.x * blockDim.x;
  for (; i < n4; i += stride) {
    float4 v = reinterpret_cast<const float4*>(in)[i];
    ushort4 o;
    o.x = f2b(v.x); o.y = f2b(v.y); o.z = f2b(v.z); o.w = f2b(v.w);
    reinterpret_cast<ushort4*>(out)[i] = o;
  }
}

// ---------------------------------------------------------------------------
// bf16 MFMA GEMM: C[m][n] = sum_k A[m][k]*W[n][k]  (+bias, *scale)
// A:[M][1024] bf16, W:[1024][1024] bf16 (both K-contiguous).
// Tile 128x128, BK=64, 256 thr = 4 waves (2x2), per-wave 2x2 of 32x32 frags.
// Staging via global_load_lds width-16 (linear LDS, m97 structure).
// MODE 0: fp32 out row-major.  MODE 1: bf16 out in (B,H,T,D).
// ---------------------------------------------------------------------------
template<int MODE>
__global__ __launch_bounds__(256)
void gemm_bf16(const u16* __restrict__ A, const u16* __restrict__ W,
               const float* __restrict__ bias, void* __restrict__ outp, float scale)
{
  __shared__ __attribute__((aligned(16))) u16 As[128 * 64];
  __shared__ __attribute__((aligned(16))) u16 Bs[128 * 64];
  const int tid  = threadIdx.x;
  const int lane = tid & 63;
  const int wid  = tid >> 6;
  const int wm = wid >> 1, wn = wid & 1;
  const int l31 = lane & 31, hh = lane >> 5;
  const int bm = blockIdx.x * 128, bn = blockIdx.y * 128;

  f32x16 acc[2][2] = {};

  for (int k0 = 0; k0 < EMBED; k0 += 64) {
    __syncthreads();
#pragma unroll
    for (int r = 0; r < 4; ++r) {
      const int u = tid + r * 256;          // 16B chunk id: row = u>>3, c = u&7
      const int row = u >> 3, c = u & 7;
      __builtin_amdgcn_global_load_lds(
          (gu32*)(A + (size_t)(bm + row) * EMBED + k0 + c * 8),
          (lu32*)(As + (size_t)u * 8), 16, 0, 0);
      __builtin_amdgcn_global_load_lds(
          (gu32*)(W + (size_t)(bn + row) * EMBED + k0 + c * 8),
          (lu32*)(Bs + (size_t)u * 8), 16, 0, 0);
    }
    __syncthreads();   // compiler drains vmcnt before barrier

#pragma unroll
    for (int g = 0; g < 4; ++g) {           // k-group of 16
      bf16x8 af[2], bfr[2];
#pragma unroll
      for (int it = 0; it < 2; ++it) {
        const int row = wm * 64 + it * 32 + l31;
        af[it] = *reinterpret_cast<const bf16x8*>(As + row * 64 + g * 16 + hh * 8);
      }
#pragma unroll
      for (int jt = 0; jt < 2; ++jt) {
        const int row = wn * 64 + jt * 32 + l31;
        bfr[jt] = *reinterpret_cast<const bf16x8*>(Bs + row * 64 + g * 16 + hh * 8);
      }
#pragma unroll
      for (int it = 0; it < 2; ++it)
#pragma unroll
        for (int jt = 0; jt < 2; ++jt)
          acc[it][jt] = __builtin_amdgcn_mfma_f32_32x32x16_bf16(af[it], bfr[jt], acc[it][jt], 0, 0, 0);
    }
  }

  // D layout (32x32): row=(reg&3)+8*(reg>>2)+4*(lane>>5), col=lane&31
#pragma unroll
  for (int it = 0; it < 2; ++it)
#pragma unroll
    for (int jt = 0; jt < 2; ++jt) {
      const int n = bn + wn * 64 + jt * 32 + l31;
      const float bv = bias[n];
#pragma unroll
      for (int reg = 0; reg < 16; ++reg) {
        const int m = bm + wm * 64 + it * 32 + (reg & 3) + 8 * (reg >> 2) + 4 * hh;
        const float val = (acc[it][jt][reg] + bv) * scale;
        if (MODE == 0) {
          ((float*)outp)[(size_t)m * EMBED + n] = val;
        } else {
          const int b = m >> 11, t = m & (SEQL - 1);
          const int h = n >> 6,  d = n & (HDIM - 1);
          ((u16*)outp)[(((size_t)(b * HEADS + h)) * SEQL + t) * HDIM + d] = f2b(val);
        }
      }
    }
}

// ---------------------------------------------------------------------------
// Flash attention, bf16 MFMA, transposed-S structure.
// Grid (T/128, B*H); 256 thr = 4 waves; wave wq owns q rows wq*32..+31.
// S^T = mfma(K, Q)  -> lane owns ONE q-row (t = lane&31): softmax is in-lane
//   max/sum over 32 regs + one shfl_xor(32) with the partner half.
// P^T built in-register (pack to bf16 + shfl_xor(32)); O^T = mfma(V^T, P^T).
// K LDS: [s][d] 16B-chunk XOR swizzle (slot ^= s&7)          -> 4-way reads.
// V LDS: transposed [d][s], swizzle slot ^= (d&7)^(d>>3)     -> 2-way writes.
// ---------------------------------------------------------------------------
__global__ __launch_bounds__(256)
void attn_mfma(const u16* __restrict__ Qp, const u16* __restrict__ Kp,
               const u16* __restrict__ Vp, u16* __restrict__ Ob)
{
  __shared__ __attribute__((aligned(16))) u16 smem[128 * 66]; // 16.9 KB
  u16* Ks = smem;          // [64][64] swizzled   (8 KB)
  u16* Vt = smem + 4096;   // [64][64] transposed (8 KB)

  const int tid  = threadIdx.x;
  const int lane = tid & 63;
  const int wq   = tid >> 6;
  const int l31  = lane & 31, hh = lane >> 5;
  const int bh   = blockIdx.y;
  const int q0   = blockIdx.x * 128;
  const size_t kvbase = (size_t)bh * SEQL * HDIM;

  // Q fragments in registers (B-operand of mfma(K,Q)): t = q0+wq*32+l31
  bf16x8 qf[4];
  {
    const u16* qrow = Qp + kvbase + (size_t)(q0 + wq * 32 + l31) * HDIM;
#pragma unroll
    for (int g = 0; g < 4; ++g)
      qf[g] = *reinterpret_cast<const bf16x8*>(qrow + g * 16 + hh * 8);
  }

  float mrow = -INFINITY, lrow = 0.f;
  f32x16 oacc[2] = {};     // O^T tiles: d 0..31, 32..63 (col = own q-row)

  for (int s0 = 0; s0 < SEQL; s0 += 64) {
    __syncthreads();       // previous step done reading Ks/Vt
    // --- stage K via global_load_lds, source pre-swizzled (chunk ^= s&7) ---
#pragma unroll
    for (int r = 0; r < 2; ++r) {
      const int u = tid + r * 256;
      const int s = u >> 3, cc = u & 7;
      const int cg = cc ^ (s & 7);
      __builtin_amdgcn_global_load_lds(
          (gu32*)(Kp + kvbase + (size_t)(s0 + s) * HDIM + cg * 8),
          (lu32*)(Ks + (size_t)u * 8), 16, 0, 0);
    }
    // --- stage V: reg load + transposed swizzled LDS writes ---
    u16x8 vreg[2];
#pragma unroll
    for (int r = 0; r < 2; ++r) {
      const int u = tid + r * 256;
      const int s = u >> 3, c = u & 7;
      vreg[r] = *reinterpret_cast<const u16x8*>(Vp + kvbase + (size_t)(s0 + s) * HDIM + c * 8);
    }
#pragma unroll
    for (int r = 0; r < 2; ++r) {
      const int u = tid + r * 256;
      const int s = u >> 3, c = u & 7;
#pragma unroll
      for (int e = 0; e < 8; ++e) {
        const int d = c * 8 + e;
        const int slot = (s >> 3) ^ (d & 7) ^ (d >> 3);
        Vt[d * 64 + slot * 8 + (s & 7)] = vreg[r][e];
      }
    }
    __syncthreads();       // drains gload_lds + ds_writes

    // --- S^T = mfma(K, Q): rows s (2 tiles of 32), col = own q-row ---
    f32x16 st[2] = {};
#pragma unroll
    for (int ts = 0; ts < 2; ++ts) {
      const int srow = ts * 32 + l31;
#pragma unroll
      for (int g = 0; g < 4; ++g) {
        const int slot = (g * 2 + hh) ^ (srow & 7);
        bf16x8 kf = *reinterpret_cast<const bf16x8*>(Ks + srow * 64 + slot * 8);
        st[ts] = __builtin_amdgcn_mfma_f32_32x32x16_bf16(kf, qf[g], st[ts], 0, 0, 0);
      }
    }

    // --- online softmax: all 32 values in-lane belong to row t=l31 ---
    float mx = -INFINITY;
#pragma unroll
    for (int ts = 0; ts < 2; ++ts)
#pragma unroll
      for (int rg = 0; rg < 16; ++rg) mx = fmaxf(mx, st[ts][rg]);
    mx = fmaxf(mx, __shfl_xor(mx, 32));
    const float mnew = fmaxf(mrow, mx);
    const float alpha = __expf(mrow - mnew);
    float rsum = 0.f;
#pragma unroll
    for (int ts = 0; ts < 2; ++ts)
#pragma unroll
      for (int rg = 0; rg < 16; ++rg) {
        const float p = __expf(st[ts][rg] - mnew);
        st[ts][rg] = p;
        rsum += p;
      }
    rsum += __shfl_xor(rsum, 32);
    lrow = lrow * alpha + rsum;
    mrow = mnew;
#pragma unroll
    for (int jd = 0; jd < 2; ++jd)
#pragma unroll
      for (int rg = 0; rg < 16; ++rg) oacc[jd][rg] *= alpha;

    // --- P^T B-frags: s-group gs holds s = gs*16 + hh*8 + i ---
    bf16x8 pb[4];
#pragma unroll
    for (int ts = 0; ts < 2; ++ts)
#pragma unroll
      for (int gl = 0; gl < 2; ++gl) {
        const int rb = gl * 8;
        const uint32_t A0 = pk2(st[ts][rb + 0], st[ts][rb + 1]);
        const uint32_t A1 = pk2(st[ts][rb + 2], st[ts][rb + 3]);
        const uint32_t B0 = pk2(st[ts][rb + 4], st[ts][rb + 5]);
        const uint32_t B1 = pk2(st[ts][rb + 6], st[ts][rb + 7]);
        const uint32_t sA0 = __shfl_xor(A0, 32);
        const uint32_t sA1 = __shfl_xor(A1, 32);
        const uint32_t sB0 = __shfl_xor(B0, 32);
        const uint32_t sB1 = __shfl_xor(B1, 32);
        union { uint32_t w[4]; bf16x8 v; } f;
        f.w[0] = hh ? sB0 : A0;
        f.w[1] = hh ? sB1 : A1;
        f.w[2] = hh ? B0  : sA0;
        f.w[3] = hh ? B1  : sA1;
        pb[ts * 2 + gl] = f.v;
      }

    // --- O^T += mfma(V^T, P^T) ---
#pragma unroll
    for (int gs = 0; gs < 4; ++gs)
#pragma unroll
      for (int jd = 0; jd < 2; ++jd) {
        const int drow = jd * 32 + l31;
        const int slot = (gs * 2 + hh) ^ (drow & 7) ^ (drow >> 3);
        bf16x8 vf = *reinterpret_cast<const bf16x8*>(Vt + drow * 64 + slot * 8);
        oacc[jd] = __builtin_amdgcn_mfma_f32_32x32x16_bf16(vf, pb[gs], oacc[jd], 0, 0, 0);
      }
  }

  // --- epilogue: normalize, transpose via LDS, coalesced bf16 store ---
  __syncthreads();                 // done with Ks/Vt; reuse smem as Os[128][66]
  u16* Os = smem;
  const float inv = 1.f / lrow;
  const int trow = wq * 32 + l31;
#pragma unroll
  for (int jd = 0; jd < 2; ++jd)
#pragma unroll
    for (int q = 0; q < 4; ++q) {
      const int dbase = jd * 32 + 8 * q + 4 * hh;
      const uint32_t w0 = pk2(oacc[jd][q * 4 + 0] * inv, oacc[jd][q * 4 + 1] * inv);
      const uint32_t w1 = pk2(oacc[jd][q * 4 + 2] * inv, oacc[jd][q * 4 + 3] * inv);
      *reinterpret_cast<uint32_t*>(Os + trow * 66 + dbase)     = w0;
      *reinterpret_cast<uint32_t*>(Os + trow * 66 + dbase + 2) = w1;
    }
  __syncthreads();
  const int b = bh >> 4, h = bh & 15;
#pragma unroll
  for (int r = 0; r < 4; ++r) {
    const int u = tid + r * 256;
    const int row = u >> 3, c = u & 7;
    uint32_t wds[4];
#pragma unroll
    for (int i2 = 0; i2 < 4; ++i2)
      wds[i2] = *reinterpret_cast<const uint32_t*>(Os + row * 66 + c * 8 + i2 * 2);
    uint4 ov; ov.x = wds[0]; ov.y = wds[1]; ov.z = wds[2]; ov.w = wds[3];
    *reinterpret_cast<uint4*>(Ob + ((size_t)(b * SEQL + q0 + row)) * EMBED + h * 64 + c * 8) = ov;
  }
}

// ---------------------------------------------------------------------------
extern "C" void kernel_launch(void* const* d_in, const int* in_sizes, int n_in,
                              void* d_out, int out_size, void* d_ws, size_t ws_size,
                              hipStream_t stream)
{
  const float* query = (const float*)d_in[0];
  const float* key   = (const float*)d_in[1];
  const float* value = (const float*)d_in[2];
  const float* Wq    = (const float*)d_in[3];
  const float* bq    = (const float*)d_in[4];
  const float* Wk    = (const float*)d_in[5];
  const float* bk    = (const float*)d_in[6];
  const float* Wv    = (const float*)d_in[7];
  const float* bv    = (const float*)d_in[8];
  const float* Wo    = (const float*)d_in[9];
  const float* bo    = (const float*)d_in[10];
  float* out = (float*)d_out;

  const size_t NBIG = (size_t)1 << 23;   // 8192*1024
  const size_t NW   = (size_t)1 << 20;   // 1024*1024
  u16* Xq  = (u16*)d_ws;
  u16* Xk  = Xq  + NBIG;
  u16* Xv  = Xk  + NBIG;
  u16* Wqb = Xv  + NBIG;
  u16* Wkb = Wqb + NW;
  u16* Wvb = Wkb + NW;
  u16* Wob = Wvb + NW;
  u16* Qb  = Wob + NW;
  u16* Kb  = Qb  + NBIG;
  u16* Vb  = Kb  + NBIG;
  u16* Oa  = Vb  + NBIG;                 // total 120 MiB

  cvt_bf16<<<2048, 256, 0, stream>>>(query, Xq, (int)(NBIG / 4));
  cvt_bf16<<<2048, 256, 0, stream>>>(key,   Xk, (int)(NBIG / 4));
  cvt_bf16<<<2048, 256, 0, stream>>>(value, Xv, (int)(NBIG / 4));
  cvt_bf16<<<512,  256, 0, stream>>>(Wq, Wqb, (int)(NW / 4));
  cvt_bf16<<<512,  256, 0, stream>>>(Wk, Wkb, (int)(NW / 4));
  cvt_bf16<<<512,  256, 0, stream>>>(Wv, Wvb, (int)(NW / 4));
  cvt_bf16<<<512,  256, 0, stream>>>(Wo, Wob, (int)(NW / 4));

  const dim3 gg(MROWS / 128, EMBED / 128);   // (64, 8)
  gemm_bf16<1><<<gg, 256, 0, stream>>>(Xq, Wqb, bq, Qb, 0.125f);  // scale folded
  gemm_bf16<1><<<gg, 256, 0, stream>>>(Xk, Wkb, bk, Kb, 1.f);
  gemm_bf16<1><<<gg, 256, 0, stream>>>(Xv, Wvb, bv, Vb, 1.f);

  attn_mfma<<<dim3(SEQL / 128, BATCH * HEADS), 256, 0, stream>>>(Qb, Kb, Vb, Oa);

  gemm_bf16<0><<<gg, 256, 0, stream>>>(Oa, Wob, bo, out, 1.f);
}